// Round 2
// baseline (413.917 us; speedup 1.0000x reference)
//
#include <hip/hip_runtime.h>

// BeliefPlausibilityFocused: outputs are two broadcast mask tensors.
//   n_sets = 8; bel[..., j] = ((j & focal) == focal), pl[..., j] = ((j & focal) > 0).
// Input values are never read — pure store-bandwidth kernel (245 MB of writes).
// d_out = [bel | pl] flat.
//
// Each thread writes 4 consecutive float4s (64 B) per output tensor. The
// 8-channel pattern spans exactly 2 float4s (A = ch0-3, B = ch4-7); thread
// base float4 index is a multiple of 4, so every thread statically writes
// A,B,A,B — uniform instruction stream, masks computed once per thread.
// Nontemporal stores avoid L2 write-allocate thrash on the 245 MB stream.

typedef float f32x4 __attribute__((ext_vector_type(4)));

__global__ void __launch_bounds__(256)
BeliefPlausibilityFocused_35656818492191_kernel(const int* __restrict__ focal_p,
                                                float* __restrict__ out,
                                                long long n4_per_out) {
    const int focal = *focal_p;  // wave-uniform scalar load

    // Build the 8-channel masks once.
    float b[8], p[8];
#pragma unroll
    for (int j = 0; j < 8; ++j) {
        const int c = j & focal;
        b[j] = (c == focal) ? 1.0f : 0.0f;
        p[j] = (c > 0) ? 1.0f : 0.0f;
    }
    const f32x4 belA = {b[0], b[1], b[2], b[3]};
    const f32x4 belB = {b[4], b[5], b[6], b[7]};
    const f32x4 plA  = {p[0], p[1], p[2], p[3]};
    const f32x4 plB  = {p[4], p[5], p[6], p[7]};

    const long long i4 = ((long long)blockIdx.x * blockDim.x + threadIdx.x) * 4;
    f32x4* __restrict__ ob = (f32x4*)out;
    f32x4* __restrict__ op = (f32x4*)(out + 4 * n4_per_out);

    if (i4 + 4 <= n4_per_out) {
        // Fast path: base is even -> pattern A,B,A,B.
        __builtin_nontemporal_store(belA, ob + i4 + 0);
        __builtin_nontemporal_store(belB, ob + i4 + 1);
        __builtin_nontemporal_store(belA, ob + i4 + 2);
        __builtin_nontemporal_store(belB, ob + i4 + 3);
        __builtin_nontemporal_store(plA,  op + i4 + 0);
        __builtin_nontemporal_store(plB,  op + i4 + 1);
        __builtin_nontemporal_store(plA,  op + i4 + 2);
        __builtin_nontemporal_store(plB,  op + i4 + 3);
    } else {
        // Tail (unused for this shape, kept for generality).
        for (long long k = i4; k < n4_per_out; ++k) {
            const bool even = ((k & 1) == 0);
            __builtin_nontemporal_store(even ? belA : belB, ob + k);
            __builtin_nontemporal_store(even ? plA  : plB,  op + k);
        }
    }
}

extern "C" void kernel_launch(void* const* d_in, const int* in_sizes, int n_in,
                              void* d_out, int out_size, void* d_ws, size_t ws_size,
                              hipStream_t stream) {
    // d_in[0] = inputs (fp32, values unused); d_in[1] = focal (int scalar).
    const int* focal = (const int*)d_in[1];
    float* out = (float*)d_out;

    const long long per_out = (long long)out_size / 2;  // floats per output tensor
    const long long n4 = per_out / 4;                   // float4s per output tensor

    const int threads = 256;
    const long long f4_per_thread = 4;
    const int blocks = (int)((n4 + threads * f4_per_thread - 1) / (threads * f4_per_thread));
    BeliefPlausibilityFocused_35656818492191_kernel<<<blocks, threads, 0, stream>>>(
        focal, out, n4);
}

// Round 3
// 295.673 us; speedup vs baseline: 1.3999x; 1.3999x over previous
//
#include <hip/hip_runtime.h>

// BeliefPlausibilityFocused: outputs are two broadcast mask tensors.
//   n_sets = 8; bel[..., j] = ((j & focal) == focal), pl[..., j] = ((j & focal) > 0).
// Input values are never read — pure store-bandwidth kernel (245 MB of writes).
// d_out = [bel | pl] flat.
//
// R2 post-mortem: nontemporal stores inflated WRITE_SIZE 245 -> 533 MB
// (partial-line writeout, no write-combining) and regressed 2x. Regular
// stores show ~zero FETCH_SIZE (no read-for-ownership) — use them.
//
// Each thread writes 4 consecutive float4s (64 B) per output tensor. The
// 8-channel pattern spans exactly 2 float4s (A = ch0-3, B = ch4-7); thread
// base float4 index is a multiple of 4, so every thread statically writes
// A,B,A,B — uniform instruction stream, masks computed once per thread.

typedef float f32x4 __attribute__((ext_vector_type(4)));

__global__ void __launch_bounds__(256)
BeliefPlausibilityFocused_35656818492191_kernel(const int* __restrict__ focal_p,
                                                float* __restrict__ out,
                                                long long n4_per_out) {
    const int focal = *focal_p;  // wave-uniform scalar load

    // Build the 8-channel masks once.
    float b[8], p[8];
#pragma unroll
    for (int j = 0; j < 8; ++j) {
        const int c = j & focal;
        b[j] = (c == focal) ? 1.0f : 0.0f;
        p[j] = (c > 0) ? 1.0f : 0.0f;
    }
    const f32x4 belA = {b[0], b[1], b[2], b[3]};
    const f32x4 belB = {b[4], b[5], b[6], b[7]};
    const f32x4 plA  = {p[0], p[1], p[2], p[3]};
    const f32x4 plB  = {p[4], p[5], p[6], p[7]};

    const long long i4 = ((long long)blockIdx.x * blockDim.x + threadIdx.x) * 4;
    f32x4* __restrict__ ob = (f32x4*)out;
    f32x4* __restrict__ op = (f32x4*)(out + 4 * n4_per_out);

    if (i4 + 4 <= n4_per_out) {
        // Fast path: base is even -> pattern A,B,A,B.
        ob[i4 + 0] = belA;
        ob[i4 + 1] = belB;
        ob[i4 + 2] = belA;
        ob[i4 + 3] = belB;
        op[i4 + 0] = plA;
        op[i4 + 1] = plB;
        op[i4 + 2] = plA;
        op[i4 + 3] = plB;
    } else {
        // Tail (unused for this shape, kept for generality).
        for (long long k = i4; k < n4_per_out; ++k) {
            const bool even = ((k & 1) == 0);
            ob[k] = even ? belA : belB;
            op[k] = even ? plA : plB;
        }
    }
}

extern "C" void kernel_launch(void* const* d_in, const int* in_sizes, int n_in,
                              void* d_out, int out_size, void* d_ws, size_t ws_size,
                              hipStream_t stream) {
    // d_in[0] = inputs (fp32, values unused); d_in[1] = focal (int scalar).
    const int* focal = (const int*)d_in[1];
    float* out = (float*)d_out;

    const long long per_out = (long long)out_size / 2;  // floats per output tensor
    const long long n4 = per_out / 4;                   // float4s per output tensor

    const int threads = 256;
    const long long f4_per_thread = 4;
    const int blocks = (int)((n4 + threads * f4_per_thread - 1) / (threads * f4_per_thread));
    BeliefPlausibilityFocused_35656818492191_kernel<<<blocks, threads, 0, stream>>>(
        focal, out, n4);
}

// Round 4
// 265.500 us; speedup vs baseline: 1.5590x; 1.1136x over previous
//
#include <hip/hip_runtime.h>

// BeliefPlausibilityFocused: outputs are two broadcast mask tensors.
//   n_sets = 8; bel[..., j] = ((j & focal) == focal), pl[..., j] = ((j & focal) > 0).
// Input values are never read — pure store-bandwidth kernel (245 MB of writes).
// d_out = [bel | pl] flat.
//
// R2 post-mortem: nontemporal stores inflated WRITE_SIZE 245 -> 533 MB
// (partial-line writeout) — use plain stores (FETCH_SIZE ~0 shows no RFO).
// R3 post-mortem: per-thread CONSECUTIVE float4s break per-instruction
// coalescing (lanes at 64 B stride, 16 B used) — 78 us vs R1's 46 us.
// Fix: grid-stride loop (fillBufferAligned's structure, which hits 6.3 TB/s):
// every store instruction is lane-contiguous (64 x 16 B = 1 KB), and each
// thread amortizes setup over ~4 iterations. Stride is even, so each
// thread's channel half (A = ch0-3 / B = ch4-7) is fixed — selected once.

typedef float f32x4 __attribute__((ext_vector_type(4)));

__global__ void __launch_bounds__(256)
BeliefPlausibilityFocused_35656818492191_kernel(const int* __restrict__ focal_p,
                                                float* __restrict__ out,
                                                long long n4_per_out) {
    const int focal = *focal_p;  // wave-uniform scalar load

    // Build the 8-channel masks once.
    float b[8], p[8];
#pragma unroll
    for (int j = 0; j < 8; ++j) {
        const int c = j & focal;
        b[j] = (c == focal) ? 1.0f : 0.0f;
        p[j] = (c > 0) ? 1.0f : 0.0f;
    }
    const f32x4 belA = {b[0], b[1], b[2], b[3]};
    const f32x4 belB = {b[4], b[5], b[6], b[7]};
    const f32x4 plA  = {p[0], p[1], p[2], p[3]};
    const f32x4 plB  = {p[4], p[5], p[6], p[7]};

    long long idx = (long long)blockIdx.x * blockDim.x + threadIdx.x;
    const long long stride = (long long)gridDim.x * blockDim.x;  // even

    // Channel half is fixed per thread (stride is even).
    const bool even = ((idx & 1) == 0);
    const f32x4 vb = even ? belA : belB;
    const f32x4 vp = even ? plA : plB;

    f32x4* __restrict__ ob = (f32x4*)out;
    f32x4* __restrict__ op = (f32x4*)(out + 4 * n4_per_out);

    for (; idx < n4_per_out; idx += stride) {
        ob[idx] = vb;
        op[idx] = vp;
    }
}

extern "C" void kernel_launch(void* const* d_in, const int* in_sizes, int n_in,
                              void* d_out, int out_size, void* d_ws, size_t ws_size,
                              hipStream_t stream) {
    // d_in[0] = inputs (fp32, values unused); d_in[1] = focal (int scalar).
    const int* focal = (const int*)d_in[1];
    float* out = (float*)d_out;

    const long long per_out = (long long)out_size / 2;  // floats per output tensor
    const long long n4 = per_out / 4;                   // float4s per output tensor

    const int threads = 256;
    const long long f4_per_thread = 4;  // ~4 grid-stride iterations per thread
    int blocks = (int)((n4 + threads * f4_per_thread - 1) / (threads * f4_per_thread));
    BeliefPlausibilityFocused_35656818492191_kernel<<<blocks, threads, 0, stream>>>(
        focal, out, n4);
}